// Round 5
// baseline (33519.510 us; speedup 1.0000x reference)
//
#include <hip/hip_runtime.h>

// Seq2Seq LSTM (E=256,H=512,B=1024,S=128,T=128). FP32 in/out.
// Round 12: BATCH-SLICED PERSISTENT BLOCKS — the recurrence is row-parallel.
// 64 blocks x 16 batch rows; each block computes ALL 2048 gate cols for its
// rows, so h (LDS) and c (registers) are block-private for all 255 steps.
// ZERO inter-block communication -> no barriers/atomics/fences/coherence.
// W re-streamed from L2 per step (4MB/phase; 8 blocks/XCD -> ~7.4us/step L2-
// bound). K=768->512 via verified xgv vocab table (x@Wih^T has 128 distinct
// rows). 2 dispatches total. Numerics verbatim r7/r11 (3-term hi/lo MFMA,
// same slab order, same cell); FC now same 3-term MFMA scheme.

typedef unsigned short u16;
typedef __attribute__((ext_vector_type(8))) short short8;
typedef __attribute__((ext_vector_type(4))) float floatx4;

__device__ __forceinline__ float bf2f(u16 s) {
  union { unsigned int u; float f; } v; v.u = ((unsigned int)s) << 16; return v.f;
}
__device__ __forceinline__ u16 f2bf(float x) {
  union { float f; unsigned int u; } v; v.f = x;
  unsigned int r = (v.u + 0x7FFFu + ((v.u >> 16) & 1u)) >> 16;
  return (u16)r;
}
__device__ __forceinline__ void split2(float x, u16* hi, u16* lo) {
  u16 h = f2bf(x);
  *hi = h;
  *lo = f2bf(x - bf2f(h));
}
__device__ __forceinline__ float sigm(float x) { return 1.0f / (1.0f + expf(-x)); }

#define MFMA16 __builtin_amdgcn_mfma_f32_16x16x32_bf16

// ---------------------------------------------------------------- prep ------
__global__ __launch_bounds__(256) void prep_m(
    const float* __restrict__ e_wih, const float* __restrict__ e_whh,
    const float* __restrict__ e_bih, const float* __restrict__ e_bhh,
    const float* __restrict__ d_wih, const float* __restrict__ d_whh,
    const float* __restrict__ d_bih, const float* __restrict__ d_bhh,
    const float* __restrict__ emb, const float* __restrict__ dec_emb,
    const float* __restrict__ fc_w, const float* __restrict__ fc_b,
    u16* __restrict__ WhiE, u16* __restrict__ WloE,
    u16* __restrict__ WhiD, u16* __restrict__ WloD,
    float* __restrict__ bcE, float* __restrict__ bcD,
    float* __restrict__ xgvE, float* __restrict__ xgvD,
    u16* __restrict__ fwHi, u16* __restrict__ fwLo,
    float* __restrict__ fcb, float* __restrict__ out) {
  int idx0 = blockIdx.x * blockDim.x + threadIdx.x;
  int stride = gridDim.x * blockDim.x;
  // recurrent weights, interleaved gate rows (rr = unit*4 + gate), K=512
  for (int i = idx0; i < 2048 * 512; i += stride) {
    int rr = i >> 9, k = i & 511;
    int j = rr >> 2, g = rr & 3;
    int orig = g * 512 + j;  // reference gate order i,f,g,o
    split2(e_whh[orig * 512 + k], &WhiE[i], &WloE[i]);
    split2(d_whh[orig * 512 + k], &WhiD[i], &WloD[i]);
  }
  for (int i = idx0; i < 2048; i += stride) {
    int j = i >> 2, g = i & 3, orig = g * 512 + j;
    bcE[i] = e_bih[orig] + e_bhh[orig];
    bcD[i] = d_bih[orig] + d_bhh[orig];
  }
  // vocab x-gate tables: xgv[v][rr] = dot(emb[v], wih[orig]) in fp32
  for (int i = idx0; i < 2 * 128 * 2048; i += stride) {
    int ph = (i >= 128 * 2048) ? 1 : 0;
    int ii = ph ? i - 128 * 2048 : i;
    int v = ii >> 11, rr = ii & 2047;
    int j = rr >> 2, g = rr & 3;
    int orig = g * 512 + j;
    const float* er = (ph ? dec_emb : emb) + v * 256;
    const float* wr = (ph ? d_wih : e_wih) + orig * 256;
    float s = 0.0f;
#pragma unroll 4
    for (int e = 0; e < 256; e += 4) {
      floatx4 ev = *(const floatx4*)(er + e);
      floatx4 wv = *(const floatx4*)(wr + e);
      s += ev[0] * wv[0] + ev[1] * wv[1] + ev[2] * wv[2] + ev[3] * wv[3];
    }
    (ph ? xgvD : xgvE)[v * 2048 + rr] = s;
  }
  // fc weights hi/lo split, natural layout [v][k]
  for (int i = idx0; i < 128 * 512; i += stride)
    split2(fc_w[i], &fwHi[i], &fwLo[i]);
  for (int i = idx0; i < 128; i += stride) fcb[i] = fc_b[i];
  for (int i = idx0; i < 1024 * 128; i += stride)
    out[(i >> 7) * 16384 + (i & 127)] = 0.0f;  // out[:,0,:] = 0
}

// --------------------------------------------------------- main (1 launch) --
// 64 blocks x 512 threads (8 waves, 2/SIMD). Block owns batch rows
// [b0, b0+16). Per step: gates GEMM M=16, N=2048, K=512 (wave w owns gate
// cols [w*256,(w+1)*256) = 16 N-tiles); cell fused per wave; h hi/lo planes
// in LDS (stride 520 u16, 16B-aligned rows); c in registers (16/lane).
// Decoder: FC (M=16, N=128, K=512) fused, 1 vocab-tile per wave.
__global__ __launch_bounds__(512, 2) void seq2seq_block(
    const int* __restrict__ src, const int* __restrict__ tgt,
    const u16* __restrict__ WhiE, const u16* __restrict__ WloE,
    const u16* __restrict__ WhiD, const u16* __restrict__ WloD,
    const float* __restrict__ bcE, const float* __restrict__ bcD,
    const float* __restrict__ xgvE, const float* __restrict__ xgvD,
    const u16* __restrict__ fwHi, const u16* __restrict__ fwLo,
    const float* __restrict__ fcb, float* __restrict__ out) {
  __shared__ __align__(16) u16 hHi_l[16 * 520];
  __shared__ __align__(16) u16 hLo_l[16 * 520];
  __shared__ __align__(16) float gsc[8][16 * 36];  // per-wave gate scratch
  __shared__ int sidx[16];

  const int tid = threadIdx.x;
  const int b0 = blockIdx.x * 16;
  const int wv = tid >> 6;        // wave 0..7
  const int lane = tid & 63;
  const int lr = lane & 15;       // A row / B row-in-tile / C col
  const int lq = lane >> 4;       // k-chunk / C row-group

  // init h = 0
  for (int i = tid; i < 16 * 520; i += 512) { hHi_l[i] = 0; hLo_l[i] = 0; }
  __syncthreads();

  float creg[16];
#pragma unroll
  for (int i = 0; i < 16; ++i) creg[i] = 0.0f;

  const int aoff = lr * 520 + lq * 8;  // A-frag LDS base (u16 index)
  const u16* pfh = fwHi + (wv * 16 + lr) * 512 + lq * 8;
  const u16* pfl = fwLo + (wv * 16 + lr) * 512 + lq * 8;

  for (int phase = 0; phase < 2; ++phase) {
    const int* idx = phase ? tgt : src;
    const float* bc = phase ? bcD : bcE;
    const float* xgv = phase ? xgvD : xgvE;
    const int nsteps = phase ? 127 : 128;
    const u16* pbh = (phase ? WhiD : WhiE) + (wv * 256 + lr) * 512 + lq * 8;
    const u16* pbl = (phase ? WloD : WloE) + (wv * 256 + lr) * 512 + lq * 8;

    for (int t = 0; t < nsteps; ++t) {
      if (tid < 16) sidx[tid] = idx[(b0 + tid) * 128 + t];

      floatx4 acc[16];
#pragma unroll
      for (int i = 0; i < 16; ++i) acc[i] = (floatx4){0.f, 0.f, 0.f, 0.f};

      // K-loop: 16 slabs x (A-frag from LDS, 16 N-tiles direct-from-L2 B)
      const u16* bh_p = pbh;
      const u16* bl_p = pbl;
#pragma unroll 4
      for (int kk = 0; kk < 16; ++kk) {
        short8 ah = *(const short8*)&hHi_l[aoff + kk * 32];
        short8 al = *(const short8*)&hLo_l[aoff + kk * 32];
#pragma unroll
        for (int nt = 0; nt < 16; ++nt) {
          short8 bh = *(const short8*)(bh_p + nt * 8192);
          short8 bl = *(const short8*)(bl_p + nt * 8192);
          acc[nt] = MFMA16(al, bh, acc[nt], 0, 0, 0);
          acc[nt] = MFMA16(ah, bl, acc[nt], 0, 0, 0);
          acc[nt] = MFMA16(ah, bh, acc[nt], 0, 0, 0);
        }
        bh_p += 32;
        bl_p += 32;
      }
      __syncthreads();  // all waves' h reads complete before h writes

      // cell: per wave, 8 chunks of 2 N-tiles (= 8 units x 16 rows each)
      float* sc = gsc[wv];
#pragma unroll
      for (int ch = 0; ch < 8; ++ch) {
#pragma unroll
        for (int q = 0; q < 2; ++q) {
          const int nt = ch * 2 + q;
#pragma unroll
          for (int j = 0; j < 4; ++j)
            sc[(lq * 4 + j) * 36 + q * 16 + lr] = acc[nt][j];
        }
        // wave-internal LDS RAW: compiler inserts lgkmcnt (same-wave order)
#pragma unroll
        for (int k2 = 0; k2 < 2; ++k2) {
          const int ul = lq + 4 * k2;  // unit-in-chunk 0..7
          floatx4 g = *(const floatx4*)&sc[lr * 36 + ul * 4];
          const int gcol = wv * 256 + ch * 32 + ul * 4;
          floatx4 bg = *(const floatx4*)&bc[gcol];
          floatx4 xg = *(const floatx4*)&xgv[sidx[lr] * 2048 + gcol];
          float gi = g[0] + bg[0] + xg[0];
          float gf = g[1] + bg[1] + xg[1];
          float gg = g[2] + bg[2] + xg[2];
          float go = g[3] + bg[3] + xg[3];
          const int ci = ch * 2 + k2;
          float cn = sigm(gf) * creg[ci] + sigm(gi) * tanhf(gg);
          creg[ci] = cn;
          float h = sigm(go) * tanhf(cn);
          u16 hi, lo;
          split2(h, &hi, &lo);
          const int hcol = wv * 64 + ch * 8 + ul;
          hHi_l[lr * 520 + hcol] = hi;
          hLo_l[lr * 520 + hcol] = lo;
        }
      }
      __syncthreads();  // h complete for next step / FC

      // fused FC (decoder): out[:, t+1, :] = h @ fc_w^T + fc_b
      if (phase == 1) {
        floatx4 fac = {0.f, 0.f, 0.f, 0.f};
#pragma unroll
        for (int kk = 0; kk < 16; ++kk) {
          short8 ah = *(const short8*)&hHi_l[aoff + kk * 32];
          short8 al = *(const short8*)&hLo_l[aoff + kk * 32];
          short8 fh = *(const short8*)(pfh + kk * 32);
          short8 fl = *(const short8*)(pfl + kk * 32);
          fac = MFMA16(al, fh, fac, 0, 0, 0);
          fac = MFMA16(ah, fl, fac, 0, 0, 0);
          fac = MFMA16(ah, fh, fac, 0, 0, 0);
        }
        const int v = wv * 16 + lr;
        const float bias = fcb[v];
#pragma unroll
        for (int j = 0; j < 4; ++j)
          out[(b0 + lq * 4 + j) * 16384 + (t + 1) * 128 + v] = fac[j] + bias;
      }
    }
  }
}

// ---------------------------------------------------------------- launch ----
extern "C" void kernel_launch(void* const* d_in, const int* in_sizes, int n_in,
                              void* d_out, int out_size, void* d_ws, size_t ws_size,
                              hipStream_t stream) {
  const int* src = (const int*)d_in[0];
  const int* tgt = (const int*)d_in[1];
  const float* emb = (const float*)d_in[2];
  const float* dec_emb = (const float*)d_in[3];
  const float* e_wih = (const float*)d_in[4];
  const float* e_whh = (const float*)d_in[5];
  const float* e_bih = (const float*)d_in[6];
  const float* e_bhh = (const float*)d_in[7];
  const float* d_wih = (const float*)d_in[8];
  const float* d_whh = (const float*)d_in[9];
  const float* d_bih = (const float*)d_in[10];
  const float* d_bhh = (const float*)d_in[11];
  const float* fc_w = (const float*)d_in[12];
  const float* fc_b = (const float*)d_in[13];
  float* out = (float*)d_out;

  char* ws = (char*)d_ws;
  u16* WhiE = (u16*)(ws + 0);              // 2,097,152
  u16* WloE = (u16*)(ws + 2097152);        // 2,097,152
  u16* WhiD = (u16*)(ws + 4194304);        // 2,097,152
  u16* WloD = (u16*)(ws + 6291456);        // 2,097,152
  float* bcE = (float*)(ws + 8388608);     // 8,192
  float* bcD = (float*)(ws + 8396800);     // 8,192
  float* xgvE = (float*)(ws + 8404992);    // 1,048,576
  float* xgvD = (float*)(ws + 9453568);    // 1,048,576
  u16* fwHi = (u16*)(ws + 10502144);       // 131,072
  u16* fwLo = (u16*)(ws + 10633216);       // 131,072
  float* fcb = (float*)(ws + 10764288);    // 512   (total ~10.8 MB)

  prep_m<<<1024, 256, 0, stream>>>(e_wih, e_whh, e_bih, e_bhh,
                                   d_wih, d_whh, d_bih, d_bhh,
                                   emb, dec_emb, fc_w, fc_b,
                                   WhiE, WloE, WhiD, WloD, bcE, bcD,
                                   xgvE, xgvD, fwHi, fwLo, fcb, out);

  seq2seq_block<<<64, 512, 0, stream>>>(src, tgt,
                                        WhiE, WloE, WhiD, WloD,
                                        bcE, bcD, xgvE, xgvD,
                                        fwHi, fwLo, fcb, out);
}

// Round 6
// 12482.669 us; speedup vs baseline: 2.6853x; 2.6853x over previous
//
#include <hip/hip_runtime.h>

// Seq2Seq LSTM (E=256,H=512,B=1024,S=128,T=128). FP32 in/out.
// Round 13: r7's proven relauncher + 64x64-tile GEMM structure, with the
// measured stalls fixed (guide ladder m97/T2/T4):
//  1. K=768->512 via fp32 xgv vocab table (r11/r12-verified).
//  2. global_load_lds width=16 staging from PRE-TILED "LDS-image" layouts
//     (W imaged in prep; h imaged by the cell writer). Zero staging VGPRs.
//  3. 3-deep LDS buffers + counted vmcnt(4) + single raw s_barrier per slab
//     (loads stay in flight across barriers; no per-slab vmcnt(0) drain).
//  4. XOR chunk-swizzle (c^=(r>>1)&3) baked into the global images and the
//     ds_read addresses -> frag reads bank-conflict-free; gload_lds linear.
// Cell / gl-exchange / FC math verbatim r7/r11 (verified, absmax 4.9e-4).

typedef unsigned short u16;
typedef unsigned int u32;
typedef __attribute__((ext_vector_type(8))) short short8;
typedef __attribute__((ext_vector_type(4))) float floatx4;

__device__ __forceinline__ float bf2f(u16 s) {
  union { unsigned int u; float f; } v; v.u = ((unsigned int)s) << 16; return v.f;
}
__device__ __forceinline__ u16 f2bf(float x) {
  union { float f; unsigned int u; } v; v.f = x;
  unsigned int r = (v.u + 0x7FFFu + ((v.u >> 16) & 1u)) >> 16;
  return (u16)r;
}
__device__ __forceinline__ void split2(float x, u16* hi, u16* lo) {
  u16 h = f2bf(x);
  *hi = h;
  *lo = f2bf(x - bf2f(h));
}
__device__ __forceinline__ float sigm(float x) { return 1.0f / (1.0f + expf(-x)); }

#define MFMA16 __builtin_amdgcn_mfma_f32_16x16x32_bf16

// swizzled u16 offset within a [64 rows][4 chunks of 8 u16] tile
__device__ __forceinline__ int swz(int r, int c) {
  return r * 32 + ((c ^ ((r >> 1) & 3)) << 3);
}

__device__ __forceinline__ void gll16(const u16* g, u16* l) {
  __builtin_amdgcn_global_load_lds(
      (const __attribute__((address_space(1))) u32*)g,
      (__attribute__((address_space(3))) u32*)l, 16, 0, 0);
}

// ---------------------------------------------------------------- prep ------
__global__ __launch_bounds__(256) void prep_m(
    const float* __restrict__ e_wih, const float* __restrict__ e_whh,
    const float* __restrict__ e_bih, const float* __restrict__ e_bhh,
    const float* __restrict__ d_wih, const float* __restrict__ d_whh,
    const float* __restrict__ d_bih, const float* __restrict__ d_bhh,
    const float* __restrict__ emb, const float* __restrict__ dec_emb,
    const float* __restrict__ fc_w, const float* __restrict__ fc_b,
    u16* __restrict__ WhiE, u16* __restrict__ WloE,
    u16* __restrict__ WhiD, u16* __restrict__ WloD,
    float* __restrict__ bcE, float* __restrict__ bcD,
    float* __restrict__ xgvE, float* __restrict__ xgvD,
    float* __restrict__ fwT, float* __restrict__ fcb,
    u16* __restrict__ hHi, u16* __restrict__ hLo,
    float* __restrict__ c, float* __restrict__ out) {
  int idx0 = blockIdx.x * blockDim.x + threadIdx.x;
  int stride = gridDim.x * blockDim.x;
  // Whh -> swizzled image: tile (bx*16+kk) holds W[bx*64+r][kk*32+kcol],
  // rr = interleaved gate row (unit*4+gate) = image row coordinate.
  for (int i = idx0; i < 2048 * 512; i += stride) {
    int rr = i >> 9, k = i & 511;
    int j = rr >> 2, g = rr & 3;
    int orig = g * 512 + j;  // reference gate order i,f,g,o
    int bx = rr >> 6, r = rr & 63, kk = k >> 5, kcol = k & 31;
    int iidx = (bx * 16 + kk) * 2048 + swz(r, kcol >> 3) + (kcol & 7);
    split2(e_whh[orig * 512 + k], &WhiE[iidx], &WloE[iidx]);
    split2(d_whh[orig * 512 + k], &WhiD[iidx], &WloD[iidx]);
  }
  for (int i = idx0; i < 2048; i += stride) {
    int j = i >> 2, g = i & 3, orig = g * 512 + j;
    bcE[i] = e_bih[orig] + e_bhh[orig];
    bcD[i] = d_bih[orig] + d_bhh[orig];
  }
  // vocab x-gate tables: xgv[v][rr] = dot(emb[v], wih[orig]) in fp32
  for (int i = idx0; i < 2 * 128 * 2048; i += stride) {
    int ph = (i >= 128 * 2048) ? 1 : 0;
    int ii = ph ? i - 128 * 2048 : i;
    int v = ii >> 11, rr = ii & 2047;
    int j = rr >> 2, g = rr & 3;
    int orig = g * 512 + j;
    const float* er = (ph ? dec_emb : emb) + v * 256;
    const float* wr = (ph ? d_wih : e_wih) + orig * 256;
    float s = 0.0f;
#pragma unroll 4
    for (int e = 0; e < 256; e += 4) {
      floatx4 ev = *(const floatx4*)(er + e);
      floatx4 wv = *(const floatx4*)(wr + e);
      s += ev[0] * wv[0] + ev[1] * wv[1] + ev[2] * wv[2] + ev[3] * wv[3];
    }
    (ph ? xgvD : xgvE)[v * 2048 + rr] = s;
  }
  for (int i = idx0; i < 128 * 512; i += stride) {
    int v = i >> 9, k = i & 511;
    fwT[k * 128 + v] = fc_w[i];
  }
  for (int i = idx0; i < 128; i += stride) fcb[i] = fc_b[i];
  for (int i = idx0; i < 1024 * 512; i += stride) {
    hHi[i] = 0; hLo[i] = 0; c[i] = 0.0f;
  }
  for (int i = idx0; i < 1024 * 128; i += stride)
    out[(i >> 7) * 16384 + (i & 127)] = 0.0f;  // out[:,0,:] = 0
}

// ------------------------------------------------------------ lstm step -----
// grid (32,16): bx -> 64 gate cols (interleaved), by -> 64 batch rows. 256thr.
// 16 slabs of K=32; per slab: 4x global_load_lds (16KB contiguous image
// chunk), counted vmcnt(4)+s_barrier, 8 swizzled ds_read_b128, 12 MFMA.
__global__ __launch_bounds__(256) void lstm_step_i(
    const int* __restrict__ idx, int t,
    const u16* __restrict__ Whi, const u16* __restrict__ Wlo,  // images
    const float* __restrict__ xgv,                             // (128,2048)
    const float* __restrict__ bc,                              // (2048)
    const u16* __restrict__ hHi_in, const u16* __restrict__ hLo_in,  // images
    u16* __restrict__ hHi_out, u16* __restrict__ hLo_out,            // images
    float* __restrict__ c) {
  __shared__ __align__(16) u16 sbuf[3][4][2048];  // 48 KB, 3-deep x 4 planes
  __shared__ int sidx[64];
  const int tid = threadIdx.x;
  const int bx = blockIdx.x, by = blockIdx.y;
  const int m0 = by * 64, n0 = bx * 64;
  const int w = tid >> 6, lane = tid & 63;

  if (tid < 64) sidx[tid] = idx[(m0 + tid) * 128 + t];

  // staging source bases: per-lane 16B of the contiguous 4KB slab chunk
  const int soff = w * 512 + (lane << 3);
  const u16* Ah = hHi_in + by * 32768 + soff;
  const u16* Al = hLo_in + by * 32768 + soff;
  const u16* Bh = Whi + bx * 32768 + soff;
  const u16* Bl = Wlo + bx * 32768 + soff;

#define STAGE(KK, BUF)                       \
  {                                          \
    u16* lb = (u16*)sbuf[BUF] + w * 512;     \
    gll16(Ah + (KK) * 2048, lb);             \
    gll16(Al + (KK) * 2048, lb + 2048);      \
    gll16(Bh + (KK) * 2048, lb + 4096);      \
    gll16(Bl + (KK) * 2048, lb + 6144);      \
  }

  const int wm = w & 1, wn = w >> 1;
  const int lr = lane & 15, lq = lane >> 4;
  const int ra0 = wm * 32 + lr, ra1 = ra0 + 16;
  const int rb0 = wn * 32 + lr, rb1 = rb0 + 16;
  const int oA0 = swz(ra0, lq), oA1 = swz(ra1, lq);
  const int oB0 = swz(rb0, lq), oB1 = swz(rb1, lq);

  floatx4 acc00 = {0.f, 0.f, 0.f, 0.f}, acc01 = {0.f, 0.f, 0.f, 0.f};
  floatx4 acc10 = {0.f, 0.f, 0.f, 0.f}, acc11 = {0.f, 0.f, 0.f, 0.f};

  STAGE(0, 0)
  STAGE(1, 1)

#pragma unroll
  for (int kk = 0; kk < 16; ++kk) {
    // wait: slab kk landed (outstanding <= {kk+1}'s 4); then all waves sync.
    if (kk == 15)
      asm volatile("s_waitcnt vmcnt(0)\n\ts_barrier" ::: "memory");
    else
      asm volatile("s_waitcnt vmcnt(4)\n\ts_barrier" ::: "memory");
    const u16* pb = (const u16*)sbuf[kk % 3];
    short8 ah0 = *(const short8*)(pb + oA0);
    short8 ah1 = *(const short8*)(pb + oA1);
    short8 al0 = *(const short8*)(pb + 2048 + oA0);
    short8 al1 = *(const short8*)(pb + 2048 + oA1);
    short8 bh0 = *(const short8*)(pb + 4096 + oB0);
    short8 bh1 = *(const short8*)(pb + 4096 + oB1);
    short8 bl0 = *(const short8*)(pb + 6144 + oB0);
    short8 bl1 = *(const short8*)(pb + 6144 + oB1);
    acc00 = MFMA16(al0, bh0, acc00, 0, 0, 0);
    acc00 = MFMA16(ah0, bl0, acc00, 0, 0, 0);
    acc00 = MFMA16(ah0, bh0, acc00, 0, 0, 0);
    acc01 = MFMA16(al0, bh1, acc01, 0, 0, 0);
    acc01 = MFMA16(ah0, bl1, acc01, 0, 0, 0);
    acc01 = MFMA16(ah0, bh1, acc01, 0, 0, 0);
    acc10 = MFMA16(al1, bh0, acc10, 0, 0, 0);
    acc10 = MFMA16(ah1, bl0, acc10, 0, 0, 0);
    acc10 = MFMA16(ah1, bh0, acc10, 0, 0, 0);
    acc11 = MFMA16(al1, bh1, acc11, 0, 0, 0);
    acc11 = MFMA16(ah1, bl1, acc11, 0, 0, 0);
    acc11 = MFMA16(ah1, bh1, acc11, 0, 0, 0);
    // issue slab kk+2: safe, everyone passed this slab's barrier (its target
    // buffer's readers were slab kk-1).
    if (kk < 14) STAGE(kk + 2, (kk + 2) % 3)
  }
  __syncthreads();  // all frag reads done before sbuf is reused as gl

  // gates -> LDS fp32 (stride 68 floats; reuses sbuf)
  float* gl = (float*)sbuf;
  const int rowb = wm * 32 + lq * 4;
  const int colb = wn * 32 + lr;
#pragma unroll
  for (int j = 0; j < 4; ++j) {
    gl[(rowb + j) * 68 + colb] = acc00[j];
    gl[(rowb + j) * 68 + colb + 16] = acc01[j];
    gl[(rowb + 16 + j) * 68 + colb] = acc10[j];
    gl[(rowb + 16 + j) * 68 + colb + 16] = acc11[j];
  }
  __syncthreads();

  // fused LSTM cell: 64 rows x 16 units; gates = MFMA h-part + xgv + bias.
#pragma unroll
  for (int ii = 0; ii < 4; ++ii) {
    int pp = ii * 256 + tid;
    int row = pp >> 4;
    int u = pp & 15;
    const float* gp = gl + row * 68 + u * 4;
    floatx4 bg = *(const floatx4*)(bc + n0 + u * 4);
    floatx4 xg = *(const floatx4*)(xgv + sidx[row] * 2048 + n0 + u * 4);
    float gi = gp[0] + bg[0] + xg[0];
    float gf = gp[1] + bg[1] + xg[1];
    float gg = gp[2] + bg[2] + xg[2];
    float go = gp[3] + bg[3] + xg[3];
    int gu = bx * 16 + u;
    int ci = (m0 + row) * 512 + gu;
    float cold = c[ci];
    float cn = sigm(gf) * cold + sigm(gi) * tanhf(gg);
    c[ci] = cn;
    float h = sigm(go) * tanhf(cn);
    u16 hi, lo;
    split2(h, &hi, &lo);
    // store h in swizzled image layout for next step's global_load_lds
    int iidx = (by * 16 + (gu >> 5)) * 2048 + swz(row, (gu & 31) >> 3) + (gu & 7);
    hHi_out[iidx] = hi;
    hLo_out[iidx] = lo;
  }
}

// --------------------------------------------------------------- fc step ----
// out[:, t+1, :] = h @ fc_w^T + fc_b. grid (128), 256 thr. r7 verbatim except
// h staging reads the swizzled image layout.
__global__ __launch_bounds__(256) void fc_step_v(
    const u16* __restrict__ hHi, const u16* __restrict__ hLo,  // images
    const float* __restrict__ fwT,  // (512,128) = fc_w^T
    const float* __restrict__ fcb,  // (128)
    float* __restrict__ out, int t) {
  __shared__ float smH[4096];  // 8 rows x 512; reused as reduce scratch
  const int tid = threadIdx.x;
  const int b0 = blockIdx.x * 8;
  {
    const int r = b0 + (tid >> 5);
    const int rloc = r & 63;
    const int u0 = (tid & 31) * 16;
    const int tile = ((r >> 6) * 16 + (u0 >> 5)) * 2048 + rloc * 32;
    const int c0 = (u0 & 31) >> 3;  // 0 or 2
    const int sw = (rloc >> 1) & 3;
    const int i0 = tile + ((c0 ^ sw) << 3);
    const int i1 = tile + (((c0 + 1) ^ sw) << 3);
    short8 vh = *(const short8*)(hHi + i0);
    short8 vl = *(const short8*)(hLo + i0);
    short8 vh2 = *(const short8*)(hHi + i1);
    short8 vl2 = *(const short8*)(hLo + i1);
    float* d = &smH[tid * 16];
#pragma unroll
    for (int j = 0; j < 8; ++j) d[j] = bf2f((u16)vh[j]) + bf2f((u16)vl[j]);
#pragma unroll
    for (int j = 0; j < 8; ++j) d[8 + j] = bf2f((u16)vh2[j]) + bf2f((u16)vl2[j]);
  }
  __syncthreads();

  const int v = tid & 127;
  const int half = tid >> 7;
  float acc[8];
#pragma unroll
  for (int r0 = 0; r0 < 8; ++r0) acc[r0] = 0.0f;
  const int kbase = half * 256;
  for (int k = kbase; k < kbase + 256; ++k) {
    float w = fwT[k * 128 + v];
#pragma unroll
    for (int r0 = 0; r0 < 8; ++r0) acc[r0] += smH[r0 * 512 + k] * w;
  }
  __syncthreads();
  float* red = smH;
#pragma unroll
  for (int r0 = 0; r0 < 8; ++r0) red[half * 1024 + r0 * 128 + v] = acc[r0];
  __syncthreads();
  if (half == 0) {
    float bias = fcb[v];
#pragma unroll
    for (int r0 = 0; r0 < 8; ++r0) {
      float sum = red[r0 * 128 + v] + red[1024 + r0 * 128 + v] + bias;
      out[(b0 + r0) * 16384 + (t + 1) * 128 + v] = sum;
    }
  }
}

// ---------------------------------------------------------------- launch ----
extern "C" void kernel_launch(void* const* d_in, const int* in_sizes, int n_in,
                              void* d_out, int out_size, void* d_ws, size_t ws_size,
                              hipStream_t stream) {
  const int* src = (const int*)d_in[0];
  const int* tgt = (const int*)d_in[1];
  const float* emb = (const float*)d_in[2];
  const float* dec_emb = (const float*)d_in[3];
  const float* e_wih = (const float*)d_in[4];
  const float* e_whh = (const float*)d_in[5];
  const float* e_bih = (const float*)d_in[6];
  const float* e_bhh = (const float*)d_in[7];
  const float* d_wih = (const float*)d_in[8];
  const float* d_whh = (const float*)d_in[9];
  const float* d_bih = (const float*)d_in[10];
  const float* d_bhh = (const float*)d_in[11];
  const float* fc_w = (const float*)d_in[12];
  const float* fc_b = (const float*)d_in[13];
  float* out = (float*)d_out;

  char* ws = (char*)d_ws;
  u16* WhiE = (u16*)(ws + 0);              // 2,097,152
  u16* WloE = (u16*)(ws + 2097152);        // 2,097,152
  u16* WhiD = (u16*)(ws + 4194304);        // 2,097,152
  u16* WloD = (u16*)(ws + 6291456);        // 2,097,152
  float* bcE = (float*)(ws + 8388608);     // 8,192
  float* bcD = (float*)(ws + 8396800);     // 8,192
  float* xgvE = (float*)(ws + 8404992);    // 1,048,576
  float* xgvD = (float*)(ws + 9453568);    // 1,048,576
  float* fwT = (float*)(ws + 10502144);    // 262,144
  float* fcb = (float*)(ws + 10764288);    // 512
  u16* hHiA = (u16*)(ws + 10764800);       // 1,048,576
  u16* hLoA = (u16*)(ws + 11813376);       // 1,048,576
  u16* hHiB = (u16*)(ws + 12861952);       // 1,048,576
  u16* hLoB = (u16*)(ws + 13910528);       // 1,048,576
  float* cbuf = (float*)(ws + 14959104);   // 2,097,152  (total ~17.1 MB)

  prep_m<<<1024, 256, 0, stream>>>(e_wih, e_whh, e_bih, e_bhh,
                                   d_wih, d_whh, d_bih, d_bhh,
                                   emb, dec_emb, fc_w, fc_b,
                                   WhiE, WloE, WhiD, WloD, bcE, bcD,
                                   xgvE, xgvD, fwT, fcb,
                                   hHiA, hLoA, cbuf, out);

  dim3 gstep(32, 16);
  const u16* hHi_in = hHiA; const u16* hLo_in = hLoA;
  u16* hHi_out = hHiB; u16* hLo_out = hLoB;
  for (int t = 0; t < 128; ++t) {
    lstm_step_i<<<gstep, 256, 0, stream>>>(src, t, WhiE, WloE, xgvE, bcE,
                                           hHi_in, hLo_in, hHi_out, hLo_out,
                                           cbuf);
    const u16* th = hHi_out; hHi_out = (u16*)hHi_in; hHi_in = th;
    const u16* tl = hLo_out; hLo_out = (u16*)hLo_in; hLo_in = tl;
  }
  for (int t = 0; t < 127; ++t) {
    lstm_step_i<<<gstep, 256, 0, stream>>>(tgt, t, WhiD, WloD, xgvD, bcD,
                                           hHi_in, hLo_in, hHi_out, hLo_out,
                                           cbuf);
    const u16* th = hHi_out; hHi_out = (u16*)hHi_in; hHi_in = th;
    const u16* tl = hLo_out; hLo_out = (u16*)hLo_in; hLo_in = tl;
    fc_step_v<<<128, 256, 0, stream>>>(hHi_in, hLo_in, fwT, fcb, out, t);
  }
}

// Round 7
// 4337.387 us; speedup vs baseline: 7.7280x; 2.8779x over previous
//
#include <hip/hip_runtime.h>

// Seq2Seq LSTM (E=256,H=512,B=1024,S=128,T=128). FP32 in/out.
// Round 14: PERSISTENT kernel assembled from individually-verified pieces:
//  - GEMM core verbatim r13 (swizzled LDS images, counted vmcnt, 3-deep
//    buffers, K=512 via fp32 xgv vocab table).
//  - h exchange verbatim r9 mechanism (PASSED): agent-scope relaxed atomic
//    u32 write-through stores + agent-scope relaxed atomic u64 loads for
//    A-staging, now pipelined 3 slabs deep into the r13 LDS image.
//  - W/xgv/bc/fw: normal cached reads (read-only, prep wrote them across a
//    kernel boundary) -> W stays L2-resident for all 255 steps.
//  - per-by-group flag barrier verbatim r9 (PASSED); c in registers.
//  - FC fused into next step's K-loop: staged A-slabs of step u ARE h after
//    step u-1; +6 MFMA/slab vs fc_w image; only bx<4 writes out.
// vmcnt ledger (A=4 u64, B=2 gll16, F=1 gll16): steady 7, k=14 -> 3, k=15 -> 0.

typedef unsigned short u16;
typedef unsigned int u32;
typedef unsigned long long u64;
typedef __attribute__((ext_vector_type(8))) short short8;
typedef __attribute__((ext_vector_type(4))) float floatx4;

__device__ __forceinline__ float bf2f(u16 s) {
  union { unsigned int u; float f; } v; v.u = ((unsigned int)s) << 16; return v.f;
}
__device__ __forceinline__ u16 f2bf(float x) {
  union { float f; unsigned int u; } v; v.f = x;
  unsigned int r = (v.u + 0x7FFFu + ((v.u >> 16) & 1u)) >> 16;
  return (u16)r;
}
__device__ __forceinline__ void split2(float x, u16* hi, u16* lo) {
  u16 h = f2bf(x);
  *hi = h;
  *lo = f2bf(x - bf2f(h));
}
__device__ __forceinline__ float sigm(float x) { return 1.0f / (1.0f + expf(-x)); }

#define MFMA16 __builtin_amdgcn_mfma_f32_16x16x32_bf16
#define ALD(p) __hip_atomic_load((p), __ATOMIC_RELAXED, __HIP_MEMORY_SCOPE_AGENT)
#define AST(p, v) __hip_atomic_store((p), (v), __ATOMIC_RELAXED, __HIP_MEMORY_SCOPE_AGENT)

// swizzled u16 offset within a [rows][4 chunks of 8 u16] tile
__device__ __forceinline__ int swz(int r, int c) {
  return r * 32 + ((c ^ ((r >> 1) & 3)) << 3);
}

__device__ __forceinline__ void gll16(const u16* g, u16* l) {
  __builtin_amdgcn_global_load_lds(
      (const __attribute__((address_space(1))) u32*)g,
      (__attribute__((address_space(3))) u32*)l, 16, 0, 0);
}

// ---------------------------------------------------------------- prep ------
__global__ __launch_bounds__(256) void prep_m(
    const float* __restrict__ e_wih, const float* __restrict__ e_whh,
    const float* __restrict__ e_bih, const float* __restrict__ e_bhh,
    const float* __restrict__ d_wih, const float* __restrict__ d_whh,
    const float* __restrict__ d_bih, const float* __restrict__ d_bhh,
    const float* __restrict__ emb, const float* __restrict__ dec_emb,
    const float* __restrict__ fc_w,
    u16* __restrict__ WhiE, u16* __restrict__ WloE,
    u16* __restrict__ WhiD, u16* __restrict__ WloD,
    float* __restrict__ bcE, float* __restrict__ bcD,
    float* __restrict__ xgvE, float* __restrict__ xgvD,
    u16* __restrict__ fwImg,
    u16* __restrict__ hHiA, u16* __restrict__ hLoA,
    float* __restrict__ out, u32* __restrict__ bar) {
  int idx0 = blockIdx.x * blockDim.x + threadIdx.x;
  int stride = gridDim.x * blockDim.x;
  // Whh -> swizzled image: tile (bx*16+kk) holds W[bx*64+r][kk*32+kcol],
  // rr = interleaved gate row (unit*4+gate).
  for (int i = idx0; i < 2048 * 512; i += stride) {
    int rr = i >> 9, k = i & 511;
    int j = rr >> 2, g = rr & 3;
    int orig = g * 512 + j;  // reference gate order i,f,g,o
    int bx = rr >> 6, r = rr & 63, kk = k >> 5, kcol = k & 31;
    int iidx = (bx * 16 + kk) * 2048 + swz(r, kcol >> 3) + (kcol & 7);
    split2(e_whh[orig * 512 + k], &WhiE[iidx], &WloE[iidx]);
    split2(d_whh[orig * 512 + k], &WhiD[iidx], &WloD[iidx]);
  }
  for (int i = idx0; i < 2048; i += stride) {
    int j = i >> 2, g = i & 3, orig = g * 512 + j;
    bcE[i] = e_bih[orig] + e_bhh[orig];
    bcD[i] = d_bih[orig] + d_bhh[orig];
  }
  // vocab x-gate tables: xgv[v][rr] = dot(emb[v], wih[orig]) in fp32
  for (int i = idx0; i < 2 * 128 * 2048; i += stride) {
    int ph = (i >= 128 * 2048) ? 1 : 0;
    int ii = ph ? i - 128 * 2048 : i;
    int v = ii >> 11, rr = ii & 2047;
    int j = rr >> 2, g = rr & 3;
    int orig = g * 512 + j;
    const float* er = (ph ? dec_emb : emb) + v * 256;
    const float* wr = (ph ? d_wih : e_wih) + orig * 256;
    float s = 0.0f;
#pragma unroll 4
    for (int e = 0; e < 256; e += 4) {
      floatx4 ev = *(const floatx4*)(er + e);
      floatx4 wv = *(const floatx4*)(wr + e);
      s += ev[0] * wv[0] + ev[1] * wv[1] + ev[2] * wv[2] + ev[3] * wv[3];
    }
    (ph ? xgvD : xgvE)[v * 2048 + rr] = s;
  }
  // fc_w -> swizzled image: [bxq][kk][wn-tile][plane][16 rows][32 u16]
  for (int i = idx0; i < 128 * 512; i += stride) {
    int v = i >> 9, k = i & 511;
    int bxq = v >> 5, wn = (v >> 4) & 1, r = v & 15;
    int kk = k >> 5, q = (k & 31) >> 3, e = k & 7;
    int off = bxq * 32768 + kk * 2048 + wn * 1024 + swz(r, q) + e;
    split2(fc_w[i], &fwImg[off], &fwImg[off + 512]);
  }
  for (int i = idx0; i < 1024 * 512; i += stride) {
    hHiA[i] = 0; hLoA[i] = 0;
  }
  for (int i = idx0; i < 1024 * 128; i += stride)
    out[(i >> 7) * 16384 + (i & 127)] = 0.0f;  // out[:,0,:] = 0
  for (int i = idx0; i < 512; i += stride) bar[i] = 0u;
}

// ------------------------------------------------------- persistent body ----
// grid (32,16): bx -> 64 gate cols (interleaved), by -> 64 batch rows. 256thr.
// Per step: 16 slabs x {counted-vmcnt barrier, 8+2 swizzled ds_read_b128,
// 12+6 MFMA, ds_write A(k+1), issue A(k+3)/B(k+2)/F(k+2)}; cell; group bar.
__global__ __launch_bounds__(256, 2) void seq2seq_p(
    const int* __restrict__ src, const int* __restrict__ tgt,
    const u16* __restrict__ WhiE, const u16* __restrict__ WloE,
    const u16* __restrict__ WhiD, const u16* __restrict__ WloD,
    const float* __restrict__ bcE, const float* __restrict__ bcD,
    const float* __restrict__ xgvE, const float* __restrict__ xgvD,
    const u16* __restrict__ fwImg, const float* __restrict__ fc_b,
    u16* __restrict__ hHiA, u16* __restrict__ hLoA,
    u16* __restrict__ hHiB, u16* __restrict__ hLoB,
    float* __restrict__ out, u32* __restrict__ bar) {
  __shared__ __align__(16) u16 sbuf[3][8192];  // Ahi|Alo|Bhi|Blo, 16KB each
  __shared__ __align__(16) u16 fbuf[3][2048];  // fc_w slab, 4KB each
  __shared__ int sidx[64];
  float* gl = (float*)sbuf;

  const int tid = threadIdx.x;
  const int bx = blockIdx.x, by = blockIdx.y;
  const int m0 = by * 64, n0 = bx * 64;
  const int w = tid >> 6, lane = tid & 63;
  const int wm = w & 1, wn = w >> 1;
  const int lr = lane & 15, lq = lane >> 4;
  const int wq = w * 512;            // wave-uniform LDS u16 offset
  const int soff = wq + lane * 8;    // per-thread staging offset (u16)
  const int oA0 = swz(wm * 32 + lr, lq), oA1 = swz(wm * 32 + lr + 16, lq);
  const int oB0 = swz(wn * 32 + lr, lq), oB1 = swz(wn * 32 + lr + 16, lq);
  const int oF = swz(lr, lq);

  const u16* Fs = fwImg + (bx & 3) * 32768 + soff;
  const int vcol = ((bx & 3) * 2 + wn) * 16 + lr;
  const float fbias = fc_b[vcol];

  float creg[4] = {0.f, 0.f, 0.f, 0.f};
  u64 aP[3][4];
  u32 gen = 0;
  u16* hIa = hHiA; u16* lIa = hLoA;
  u16* hIb = hHiB; u16* lIb = hLoB;

#define ISSA(KK)                                                             \
  {                                                                          \
    const u64* s1_ = (const u64*)(Ah + (KK) * 2048);                         \
    const u64* s2_ = (const u64*)(Al + (KK) * 2048);                         \
    aP[(KK) % 3][0] = ALD(s1_);                                              \
    aP[(KK) % 3][1] = ALD(s1_ + 1);                                          \
    aP[(KK) % 3][2] = ALD(s2_);                                              \
    aP[(KK) % 3][3] = ALD(s2_ + 1);                                          \
  }
#define DSWA(KK)                                                             \
  {                                                                          \
    u64* d1_ = (u64*)&sbuf[(KK) % 3][soff];                                  \
    u64* d2_ = (u64*)&sbuf[(KK) % 3][2048 + soff];                           \
    d1_[0] = aP[(KK) % 3][0];                                                \
    d1_[1] = aP[(KK) % 3][1];                                                \
    d2_[0] = aP[(KK) % 3][2];                                                \
    d2_[1] = aP[(KK) % 3][3];                                                \
  }
#define ISSB(KK)                                                             \
  {                                                                          \
    gll16(Bh + (KK) * 2048, &sbuf[(KK) % 3][4096 + wq]);                     \
    gll16(Bl + (KK) * 2048, &sbuf[(KK) % 3][6144 + wq]);                     \
  }
#define ISSF(KK) { gll16(Fs + (KK) * 2048, &fbuf[(KK) % 3][wq]); }

#define KSTEP(KK, VM)                                                        \
  {                                                                          \
    asm volatile("s_waitcnt vmcnt(" #VM ") lgkmcnt(0)\n\ts_barrier" :::      \
                     "memory");                                              \
    const u16* pb = &sbuf[(KK) % 3][0];                                      \
    short8 ah0 = *(const short8*)(pb + oA0);                                 \
    short8 ah1 = *(const short8*)(pb + oA1);                                 \
    short8 al0 = *(const short8*)(pb + 2048 + oA0);                          \
    short8 al1 = *(const short8*)(pb + 2048 + oA1);                          \
    short8 bh0 = *(const short8*)(pb + 4096 + oB0);                          \
    short8 bh1 = *(const short8*)(pb + 4096 + oB1);                          \
    short8 bl0 = *(const short8*)(pb + 6144 + oB0);                          \
    short8 bl1 = *(const short8*)(pb + 6144 + oB1);                          \
    const u16* pf = &fbuf[(KK) % 3][wn * 1024];                              \
    short8 fh = *(const short8*)(pf + oF);                                   \
    short8 fl = *(const short8*)(pf + 512 + oF);                             \
    acc00 = MFMA16(al0, bh0, acc00, 0, 0, 0);                                \
    acc00 = MFMA16(ah0, bl0, acc00, 0, 0, 0);                                \
    acc00 = MFMA16(ah0, bh0, acc00, 0, 0, 0);                                \
    acc01 = MFMA16(al0, bh1, acc01, 0, 0, 0);                                \
    acc01 = MFMA16(ah0, bl1, acc01, 0, 0, 0);                                \
    acc01 = MFMA16(ah0, bh1, acc01, 0, 0, 0);                                \
    acc10 = MFMA16(al1, bh0, acc10, 0, 0, 0);                                \
    acc10 = MFMA16(ah1, bl0, acc10, 0, 0, 0);                                \
    acc10 = MFMA16(ah1, bh0, acc10, 0, 0, 0);                                \
    acc11 = MFMA16(al1, bh1, acc11, 0, 0, 0);                                \
    acc11 = MFMA16(ah1, bl1, acc11, 0, 0, 0);                                \
    acc11 = MFMA16(ah1, bh1, acc11, 0, 0, 0);                                \
    facL = MFMA16(al0, fh, facL, 0, 0, 0);                                   \
    facL = MFMA16(ah0, fl, facL, 0, 0, 0);                                   \
    facL = MFMA16(ah0, fh, facL, 0, 0, 0);                                   \
    facH = MFMA16(al1, fh, facH, 0, 0, 0);                                   \
    facH = MFMA16(ah1, fl, facH, 0, 0, 0);                                   \
    facH = MFMA16(ah1, fh, facH, 0, 0, 0);                                   \
    if ((KK) < 15) DSWA((KK) + 1);                                           \
    if ((KK) < 13) ISSA((KK) + 3);                                           \
    if ((KK) < 14) { ISSB((KK) + 2); ISSF((KK) + 2); }                       \
  }

  for (int phase = 0; phase < 2; ++phase) {
    const int* idxp = phase ? tgt : src;
    const float* bc = phase ? bcD : bcE;
    const float* xgv = phase ? xgvD : xgvE;
    const u16* Bh = (phase ? WhiD : WhiE) + bx * 32768 + soff;
    const u16* Bl = (phase ? WloD : WloE) + bx * 32768 + soff;

    for (int u = 0; u < 128; ++u) {
      if (tid < 64) sidx[tid] = idxp[(m0 + tid) * 128 + u];

      const u16* Ah = hIa + by * 32768 + soff;
      const u16* Al = lIa + by * 32768 + soff;

      floatx4 acc00 = {0.f, 0.f, 0.f, 0.f}, acc01 = {0.f, 0.f, 0.f, 0.f};
      floatx4 acc10 = {0.f, 0.f, 0.f, 0.f}, acc11 = {0.f, 0.f, 0.f, 0.f};
      floatx4 facL = {0.f, 0.f, 0.f, 0.f}, facH = {0.f, 0.f, 0.f, 0.f};

      // prologue: A(0) staged, then pending = A1,B0,F0,A2,B1,F1 = 14
      ISSA(0)
      DSWA(0)  // compiler auto-inserts vmcnt before use
      ISSA(1) ISSB(0) ISSF(0) ISSA(2) ISSB(1) ISSF(1)
      asm volatile("s_waitcnt lgkmcnt(0)\n\ts_barrier" ::: "memory");

      KSTEP(0, 7)  KSTEP(1, 7)  KSTEP(2, 7)  KSTEP(3, 7)
      KSTEP(4, 7)  KSTEP(5, 7)  KSTEP(6, 7)  KSTEP(7, 7)
      KSTEP(8, 7)  KSTEP(9, 7)  KSTEP(10, 7) KSTEP(11, 7)
      KSTEP(12, 7) KSTEP(13, 7) KSTEP(14, 3) KSTEP(15, 0)
      __syncthreads();  // frag reads done before sbuf reused as gl

      // fused FC: out[:, u, :] = h(after step u-1) @ fc_w^T + fc_b
      if (phase == 1 && u >= 1 && bx < 4) {
#pragma unroll
        for (int j = 0; j < 4; ++j) {
          out[(m0 + wm * 32 + lq * 4 + j) * 16384 + u * 128 + vcol] =
              facL[j] + fbias;
          out[(m0 + wm * 32 + 16 + lq * 4 + j) * 16384 + u * 128 + vcol] =
              facH[j] + fbias;
        }
      }

      // gates -> LDS fp32 (stride 68 floats; reuses sbuf)
      const int rowb = wm * 32 + lq * 4;
      const int colb = wn * 32 + lr;
#pragma unroll
      for (int j = 0; j < 4; ++j) {
        gl[(rowb + j) * 68 + colb] = acc00[j];
        gl[(rowb + j) * 68 + colb + 16] = acc01[j];
        gl[(rowb + 16 + j) * 68 + colb] = acc10[j];
        gl[(rowb + 16 + j) * 68 + colb + 16] = acc11[j];
      }
      __syncthreads();

      // fused LSTM cell (r9 partition): 2 adjacent units/thread/half, c in
      // regs, h out via agent-scope u32 write-through to swizzled image.
#pragma unroll
      for (int ii = 0; ii < 2; ++ii) {
        int pp = ii * 256 + tid;
        int row = pp >> 3;            // 0..63
        int up = (pp & 7) * 2;        // even unit-in-block
        const float* gp = gl + row * 68 + up * 4;
        const float* bp = bc + n0 + up * 4;
        const float* xp = xgv + sidx[row] * 2048 + n0 + up * 4;
        float h0, h1;
        {
          float gi = gp[0] + bp[0] + xp[0], gf = gp[1] + bp[1] + xp[1];
          float gg = gp[2] + bp[2] + xp[2], go = gp[3] + bp[3] + xp[3];
          float cn = sigm(gf) * creg[ii * 2] + sigm(gi) * tanhf(gg);
          creg[ii * 2] = cn;
          h0 = sigm(go) * tanhf(cn);
        }
        {
          float gi = gp[4] + bp[4] + xp[4], gf = gp[5] + bp[5] + xp[5];
          float gg = gp[6] + bp[6] + xp[6], go = gp[7] + bp[7] + xp[7];
          float cn = sigm(gf) * creg[ii * 2 + 1] + sigm(gi) * tanhf(gg);
          creg[ii * 2 + 1] = cn;
          h1 = sigm(go) * tanhf(cn);
        }
        int gu = bx * 16 + up;  // even global h-col
        int iidx = (by * 16 + (gu >> 5)) * 2048 + swz(row, (gu & 31) >> 3) +
                   (gu & 7);
        u16 hi0, lo0, hi1, lo1;
        split2(h0, &hi0, &lo0);
        split2(h1, &hi1, &lo1);
        AST((u32*)(hIb + iidx), (u32)hi0 | ((u32)hi1 << 16));
        AST((u32*)(lIb + iidx), (u32)lo0 | ((u32)lo1 << 16));
      }

      // ---- per-by-group barrier (r9 verbatim) ----
      ++gen;
      __syncthreads();  // drains each wave's vmcnt before s_barrier
      if (tid == 0) {
        asm volatile("s_waitcnt vmcnt(0)" ::: "memory");
        AST(&bar[(by << 5) + bx], gen);
      }
      if (tid < 32) {
        while (ALD(&bar[(by << 5) + tid]) < gen)
          __builtin_amdgcn_s_sleep(2);
      }
      asm volatile("" ::: "memory");
      __syncthreads();

      // swap h ping-pong
      u16* th = hIa; hIa = hIb; hIb = th;
      u16* tl = lIa; lIa = lIb; lIb = tl;
    }
  }
}

// ---------------------------------------------------------------- launch ----
extern "C" void kernel_launch(void* const* d_in, const int* in_sizes, int n_in,
                              void* d_out, int out_size, void* d_ws, size_t ws_size,
                              hipStream_t stream) {
  const int* src = (const int*)d_in[0];
  const int* tgt = (const int*)d_in[1];
  const float* emb = (const float*)d_in[2];
  const float* dec_emb = (const float*)d_in[3];
  const float* e_wih = (const float*)d_in[4];
  const float* e_whh = (const float*)d_in[5];
  const float* e_bih = (const float*)d_in[6];
  const float* e_bhh = (const float*)d_in[7];
  const float* d_wih = (const float*)d_in[8];
  const float* d_whh = (const float*)d_in[9];
  const float* d_bih = (const float*)d_in[10];
  const float* d_bhh = (const float*)d_in[11];
  const float* fc_w = (const float*)d_in[12];
  const float* fc_b = (const float*)d_in[13];
  float* out = (float*)d_out;

  char* ws = (char*)d_ws;
  u16* WhiE = (u16*)(ws + 0);              // 2,097,152
  u16* WloE = (u16*)(ws + 2097152);        // 2,097,152
  u16* WhiD = (u16*)(ws + 4194304);        // 2,097,152
  u16* WloD = (u16*)(ws + 6291456);        // 2,097,152
  float* bcE = (float*)(ws + 8388608);     // 8,192
  float* bcD = (float*)(ws + 8396800);     // 8,192
  float* xgvE = (float*)(ws + 8404992);    // 1,048,576
  float* xgvD = (float*)(ws + 9453568);    // 1,048,576
  u16* fwImg = (u16*)(ws + 10502144);      // 262,144
  u16* hHiA = (u16*)(ws + 10764288);       // 1,048,576
  u16* hLoA = (u16*)(ws + 11812864);       // 1,048,576
  u16* hHiB = (u16*)(ws + 12861440);       // 1,048,576
  u16* hLoB = (u16*)(ws + 13910016);       // 1,048,576
  u32* bar = (u32*)(ws + 14958592);        // 2,048   (total ~15.0 MB)

  prep_m<<<1024, 256, 0, stream>>>(e_wih, e_whh, e_bih, e_bhh,
                                   d_wih, d_whh, d_bih, d_bhh,
                                   emb, dec_emb, fc_w,
                                   WhiE, WloE, WhiD, WloD, bcE, bcD,
                                   xgvE, xgvD, fwImg, hHiA, hLoA, out, bar);

  void* ka[] = {
      (void*)&src, (void*)&tgt,
      (void*)&WhiE, (void*)&WloE, (void*)&WhiD, (void*)&WloD,
      (void*)&bcE, (void*)&bcD, (void*)&xgvE, (void*)&xgvD,
      (void*)&fwImg, (void*)&fc_b,
      (void*)&hHiA, (void*)&hLoA, (void*)&hHiB, (void*)&hLoB,
      (void*)&out, (void*)&bar};
  hipError_t ce = hipLaunchCooperativeKernel(
      (const void*)seq2seq_p, dim3(32, 16), dim3(256), ka, 0, stream);
  if (ce != hipSuccess) {
    // co-residency is structurally guaranteed (launch_bounds(256,2), 512
    // blocks = 2/CU) — plain launch is safe if cooperative path unavailable.
    (void)hipGetLastError();
    seq2seq_p<<<dim3(32, 16), 256, 0, stream>>>(
        src, tgt, WhiE, WloE, WhiD, WloD, bcE, bcD, xgvE, xgvD,
        fwImg, fc_b, hHiA, hLoA, hHiB, hLoB, out, bar);
  }
}